// Round 4
// baseline (392.228 us; speedup 1.0000x reference)
//
#include <hip/hip_runtime.h>
#include <hip/hip_fp16.h>

#define N_FEAT0 128
#define HID 64
#define NCLS 40

#define BSH 9            // log2 nodes per bucket
#define BSZ 512          // nodes per bucket
#define BCAP 12288       // slab capacity per bucket (mean 8192, sigma ~90 -> 45 sigma margin)
#define STILE 16384      // edges per scatter block

// ---------------- phase 1: LDS-binned scatter of edges into per-bucket slabs ----
// Record = (d & 511) << 17 | s   (s < 2^17 since N = 100000 < 131072).
__global__ __launch_bounds__(256) void scatter_kernel(const int* __restrict__ esrc,
                                                      const int* __restrict__ edst,
                                                      int* __restrict__ bfill,
                                                      int* __restrict__ slab, int E) {
  __shared__ int cnt[256];
  __shared__ int base[256];
  int t = threadIdx.x;
  int t0 = blockIdx.x * STILE;
  cnt[t] = 0;
  __syncthreads();

  // pass A: histogram
#pragma unroll 4
  for (int i = 0; i < STILE / 1024; ++i) {
    int e = t0 + i * 1024 + t * 4;
    if (e < E) {
      int4 d4 = *(const int4*)(edst + e);
      atomicAdd(&cnt[d4.x >> BSH], 1);
      atomicAdd(&cnt[d4.y >> BSH], 1);
      atomicAdd(&cnt[d4.z >> BSH], 1);
      atomicAdd(&cnt[d4.w >> BSH], 1);
    }
  }
  __syncthreads();
  int c = cnt[t];
  if (c > 0) base[t] = t * BCAP + atomicAdd(&bfill[t], c);
  cnt[t] = 0;
  __syncthreads();

  // pass B: binned write (tile is L2-warm from pass A)
#pragma unroll 4
  for (int i = 0; i < STILE / 1024; ++i) {
    int e = t0 + i * 1024 + t * 4;
    if (e < E) {
      int4 s4 = *(const int4*)(esrc + e);
      int4 d4 = *(const int4*)(edst + e);
#define EMIT(dd, ss)                                             \
      {                                                          \
        int b_ = (dd) >> BSH;                                    \
        int r_ = atomicAdd(&cnt[b_], 1);                         \
        slab[base[b_] + r_] = (((dd) & (BSZ - 1)) << 17) | (ss); \
      }
      EMIT(d4.x, s4.x)
      EMIT(d4.y, s4.y)
      EMIT(d4.z, s4.z)
      EMIT(d4.w, s4.w)
#undef EMIT
    }
  }
}

// ---------------- scan of bucket sizes -> bucket bases ----------------
__global__ __launch_bounds__(256) void bscan_kernel(const int* __restrict__ bfill,
                                                    int* __restrict__ bbase,
                                                    int* __restrict__ row_ptr,
                                                    int nbuck, int N) {
  __shared__ int sh[256];
  int t = threadIdx.x;
  int v = (t < nbuck) ? bfill[t] : 0;
  sh[t] = v;
  __syncthreads();
  for (int off = 1; off < 256; off <<= 1) {
    int u = (t >= off) ? sh[t - off] : 0;
    __syncthreads();
    sh[t] += u;
    __syncthreads();
  }
  if (t < nbuck) bbase[t] = sh[t] - v;  // exclusive
  if (t == 255) {
    bbase[nbuck] = sh[255];
    row_ptr[N] = sh[255];  // == E
  }
}

// ---------------- phase 2: per-bucket CSR finalize ----------------
__global__ __launch_bounds__(256) void build_kernel(const int* __restrict__ slab,
                                                    const int* __restrict__ bfill,
                                                    const int* __restrict__ bbase,
                                                    int* __restrict__ row_ptr,
                                                    float* __restrict__ dinv,
                                                    int* __restrict__ ew, int N) {
  __shared__ int cnt[512];
  __shared__ int pre[512];
  __shared__ int s2[256];
  int b = blockIdx.x;
  int t = threadIdx.x;
  int nbase = b << BSH;
  int nNodes = N - nbase;
  if (nNodes > BSZ) nNodes = BSZ;
  cnt[t] = 0;
  cnt[t + 256] = 0;
  __syncthreads();

  int sz = bfill[b];
  int sbeg = b * BCAP;
  int obase = bbase[b];

  // per-node histogram
  for (int r = t; r < sz; r += 256) atomicAdd(&cnt[((unsigned)slab[sbeg + r]) >> 17], 1);
  __syncthreads();

  // exclusive prefix over 512 counters (pair-sum + 256-wide scan)
  int a = cnt[2 * t], c = cnt[2 * t + 1];
  s2[t] = a + c;
  __syncthreads();
  for (int off = 1; off < 256; off <<= 1) {
    int u = (t >= off) ? s2[t - off] : 0;
    __syncthreads();
    s2[t] += u;
    __syncthreads();
  }
  int ex = s2[t] - (a + c);
  pre[2 * t] = ex;
  pre[2 * t + 1] = ex + a;
  __syncthreads();

  // row_ptr + dinv (coalesced)
  if (t < nNodes) {
    row_ptr[nbase + t] = obase + pre[t];
    dinv[nbase + t] = rsqrtf((float)(cnt[t] + 1));
  }
  int t2 = t + 256;
  if (t2 < nNodes) {
    row_ptr[nbase + t2] = obase + pre[t2];
    dinv[nbase + t2] = rsqrtf((float)(cnt[t2] + 1));
  }
  __syncthreads();
  cnt[t] = 0;
  cnt[t + 256] = 0;
  __syncthreads();

  // final permute: slab (coalesced read, L2-warm) -> node-ordered ew
  for (int r = t; r < sz; r += 256) {
    int rec = slab[sbeg + r];
    int dloc = ((unsigned)rec) >> 17;
    int rank = atomicAdd(&cnt[dloc], 1);
    ew[obase + pre[dloc] + rank] = rec & 0x1FFFF;  // src only; weight folded out
  }
}

// ---------------- dense GEMM with dinv row-scale epilogue, fp16 output -------
// Layer 0 only (f32 128-wide input x). G1 = (half) dinv (.) (x @ W0).
template <int K, int NC>
__global__ __launch_bounds__(256) void gemm_kernel(const float* __restrict__ A,
                                                   const float* __restrict__ W,
                                                   __half* __restrict__ Out,
                                                   const float* __restrict__ rowscale,
                                                   int N) {
  constexpr int BK = 64;
  constexpr int LDSS = 68;           // LDS row stride in floats (17 x float4)
  __shared__ float As[128 * LDSS];   // 34816 B

  int t = threadIdx.x;
  int lane = t & 63;
  int wave = t >> 6;
  int c4 = lane & 15;                // col-quad 0..15
  int qr = lane >> 4;                // row phase 0..3
  int r0 = blockIdx.x * 128;

  int wc = 4 * c4;
  if (wc > NC - 4) wc = NC - 4;
  bool cok = (wc == 4 * c4);

  float4 acc[8];
#pragma unroll
  for (int m = 0; m < 8; ++m) acc[m] = make_float4(0.f, 0.f, 0.f, 0.f);

  for (int kc = 0; kc < K; kc += BK) {
    __syncthreads();
#pragma unroll
    for (int i = 0; i < 8; ++i) {
      int idx = t + i * 256;
      int row = idx >> 4;
      int cq = idx & 15;
      int gr = r0 + row;
      if (gr >= N) gr = N - 1;
      float4 v = *(const float4*)(A + (size_t)gr * K + kc + 4 * cq);
      *(float4*)(As + row * LDSS + 4 * cq) = v;
    }
    __syncthreads();

#pragma unroll 2
    for (int kk = 0; kk < BK / 4; ++kk) {
      float4 w[4];
#pragma unroll
      for (int k = 0; k < 4; ++k)
        w[k] = *(const float4*)(W + (size_t)(kc + kk * 4 + k) * NC + wc);
#pragma unroll
      for (int m = 0; m < 8; ++m) {
        int lrow = wave * 32 + qr + 4 * m;
        float4 a = *(const float4*)(As + lrow * LDSS + kk * 4);
        acc[m].x = fmaf(a.x, w[0].x, acc[m].x);
        acc[m].y = fmaf(a.x, w[0].y, acc[m].y);
        acc[m].z = fmaf(a.x, w[0].z, acc[m].z);
        acc[m].w = fmaf(a.x, w[0].w, acc[m].w);
        acc[m].x = fmaf(a.y, w[1].x, acc[m].x);
        acc[m].y = fmaf(a.y, w[1].y, acc[m].y);
        acc[m].z = fmaf(a.y, w[1].z, acc[m].z);
        acc[m].w = fmaf(a.y, w[1].w, acc[m].w);
        acc[m].x = fmaf(a.z, w[2].x, acc[m].x);
        acc[m].y = fmaf(a.z, w[2].y, acc[m].y);
        acc[m].z = fmaf(a.z, w[2].z, acc[m].z);
        acc[m].w = fmaf(a.z, w[2].w, acc[m].w);
        acc[m].x = fmaf(a.w, w[3].x, acc[m].x);
        acc[m].y = fmaf(a.w, w[3].y, acc[m].y);
        acc[m].z = fmaf(a.w, w[3].z, acc[m].z);
        acc[m].w = fmaf(a.w, w[3].w, acc[m].w);
      }
    }
  }

  if (cok) {
#pragma unroll
    for (int m = 0; m < 8; ++m) {
      int gr = r0 + wave * 32 + qr + 4 * m;
      if (gr < N) {
        float ds = rowscale[gr];
        union { __half2 h[2]; uint2 u; } cv;
        cv.h[0] = __floats2half2_rn(ds * acc[m].x, ds * acc[m].y);
        cv.h[1] = __floats2half2_rn(ds * acc[m].z, ds * acc[m].w);
        *(uint2*)(Out + (size_t)gr * NC + wc) = cv.u;
      }
    }
  }
}

// ---------------- fused agg + GEMV: G_out = dinv (.) (relu(dinv (.) A_hat G_in) @ W) ----
// Round-4: after the agg fold, lane (eg,fo) holds exactly features fo*8..fo*8+7
// of the aggregated row -- the A-fragment for a register GEMV. Each wave
// preloads w[i][j] = W[fo*8+i][eg*8+j] (64 VGPR, amortized over ~12 nodes),
// then per node: 64 FMA + 24 shfl, overlapped with the next gather's latency.
// Deletes the separate gemm kernel and the 2x25.6MB H round-trip per layer.
template <int NC>
__global__ __launch_bounds__(256, 4) void fused_kernel(const __half* __restrict__ Gin,
                                                       const int* __restrict__ row_ptr,
                                                       const int* __restrict__ ew,
                                                       const float* __restrict__ dinv,
                                                       const float* __restrict__ W,
                                                       __half* __restrict__ Gout, int N) {
  int lane = threadIdx.x & 63;
  int eg = lane >> 3;                // edge slot / output col-block
  int fo = lane & 7;                 // feature oct
  int waveId = blockIdx.x * (blockDim.x >> 6) + (threadIdx.x >> 6);
  int NW = gridDim.x * (blockDim.x >> 6);
  int c0 = eg * 8;

  // W fragment (zeros for cols >= NC)
  float w[8][8];
#pragma unroll
  for (int i = 0; i < 8; ++i) {
    int f = fo * 8 + i;
#pragma unroll
    for (int j = 0; j < 8; ++j)
      w[i][j] = (c0 + j < NC) ? W[f * NC + c0 + j] : 0.f;
  }

  for (int v = waveId; v < N; v += NW) {
    float acc[8];
#pragma unroll
    for (int i = 0; i < 8; ++i) acc[i] = 0.f;

#define GLD(s) (*(const uint4*)(Gin + (size_t)(s) * 64 + fo * 8))
    auto addrow = [&](uint4 q) {
      const __half2* h2 = (const __half2*)&q;
#pragma unroll
      for (int i = 0; i < 4; ++i) {
        float2 f2 = __half22float2(h2[i]);
        acc[2 * i] += f2.x;
        acc[2 * i + 1] += f2.y;
      }
    };

    if (eg == 0) addrow(GLD(v));     // self-loop term
    int beg = __builtin_amdgcn_readfirstlane(row_ptr[v]);
    int end = __builtin_amdgcn_readfirstlane(row_ptr[v + 1]);
    int j = beg;
    for (; j + 16 <= end; j += 16) {
      int s0 = ew[j + eg];
      int s1 = ew[j + 8 + eg];
      uint4 a = GLD(s0);
      uint4 b = GLD(s1);
      addrow(a);
      addrow(b);
    }
    if (j + 8 <= end) {
      addrow(GLD(ew[j + eg]));
      j += 8;
    }
    {
      int idx = j + eg;
      if (idx < end) addrow(GLD(ew[idx]));
    }
#undef GLD

    // fold edge-slot groups (eg bits 3..5): lane now holds h[fo*8..fo*8+7]
#pragma unroll
    for (int m = 8; m <= 32; m <<= 1)
#pragma unroll
      for (int i = 0; i < 8; ++i) acc[i] += __shfl_xor(acc[i], m);

    float dv = dinv[v];
    float h[8];
#pragma unroll
    for (int i = 0; i < 8; ++i) h[i] = fmaxf(dv * acc[i], 0.f);

    // GEMV: partial over this lane's feature oct for cols c0..c0+7
    float pj[8];
#pragma unroll
    for (int jj = 0; jj < 8; ++jj) pj[jj] = 0.f;
#pragma unroll
    for (int i = 0; i < 8; ++i)
#pragma unroll
      for (int jj = 0; jj < 8; ++jj) pj[jj] = fmaf(h[i], w[i][jj], pj[jj]);
    // fold feature octs (fo bits 0..2)
#pragma unroll
    for (int m = 1; m <= 4; m <<= 1)
#pragma unroll
      for (int jj = 0; jj < 8; ++jj) pj[jj] += __shfl_xor(pj[jj], m);

    if (fo == 0 && c0 < NC) {
      union { __half2 h2[4]; uint4 u; } cv;
      cv.h2[0] = __floats2half2_rn(dv * pj[0], dv * pj[1]);
      cv.h2[1] = __floats2half2_rn(dv * pj[2], dv * pj[3]);
      cv.h2[2] = __floats2half2_rn(dv * pj[4], dv * pj[5]);
      cv.h2[3] = __floats2half2_rn(dv * pj[6], dv * pj[7]);
      *(uint4*)(Gout + (size_t)v * NC + c0) = cv.u;  // 16B, aligned (NC*2 % 16 == 0)
    }
  }
}

// ---------------- final sparse aggregation (f32 output) ----------------
template <int F>
__global__ __launch_bounds__(256) void agg_kernel(const __half* __restrict__ G,
                                                  const int* __restrict__ row_ptr,
                                                  const int* __restrict__ ew,
                                                  const float* __restrict__ dinv,
                                                  float* __restrict__ Hout, int N) {
  constexpr int FO = F / 8;          // feature octs: 5 for F=40
  int gid = blockIdx.x * blockDim.x + threadIdx.x;
  int v = gid >> 6;
  if (v >= N) return;
  int lane = threadIdx.x & 63;
  int eg = lane >> 3;
  int fo = lane & 7;
  bool fok = (fo < FO);
  int foc = fok ? fo : FO - 1;

  float acc[8];
#pragma unroll
  for (int i = 0; i < 8; ++i) acc[i] = 0.f;

#define GLD(s) (*(const uint4*)(G + (size_t)(s) * F + foc * 8))
  auto addrow = [&](uint4 q) {
    const __half2* h = (const __half2*)&q;
#pragma unroll
    for (int i = 0; i < 4; ++i) {
      float2 f = __half22float2(h[i]);
      acc[2 * i] += f.x;
      acc[2 * i + 1] += f.y;
    }
  };

  if (eg == 0) addrow(GLD(v));

  int beg = __builtin_amdgcn_readfirstlane(row_ptr[v]);
  int end = __builtin_amdgcn_readfirstlane(row_ptr[v + 1]);
  int j = beg;
  for (; j + 16 <= end; j += 16) {
    int s0 = ew[j + eg];
    int s1 = ew[j + 8 + eg];
    uint4 a = GLD(s0);
    uint4 b = GLD(s1);
    addrow(a);
    addrow(b);
  }
  if (j + 8 <= end) {
    addrow(GLD(ew[j + eg]));
    j += 8;
  }
  {
    int idx = j + eg;
    if (idx < end) addrow(GLD(ew[idx]));
  }
#undef GLD

#pragma unroll
  for (int m = 8; m <= 32; m <<= 1) {
#pragma unroll
    for (int i = 0; i < 8; ++i) acc[i] += __shfl_xor(acc[i], m);
  }

  if (fok) {
    float dv = dinv[v];
    float4 o0, o1;
    o0.x = fmaxf(dv * acc[0], 0.f);
    o0.y = fmaxf(dv * acc[1], 0.f);
    o0.z = fmaxf(dv * acc[2], 0.f);
    o0.w = fmaxf(dv * acc[3], 0.f);
    o1.x = fmaxf(dv * acc[4], 0.f);
    o1.y = fmaxf(dv * acc[5], 0.f);
    o1.z = fmaxf(dv * acc[6], 0.f);
    o1.w = fmaxf(dv * acc[7], 0.f);
    float4* outp = (float4*)(Hout + (size_t)v * F + fo * 8);
    outp[0] = o0;
    outp[1] = o1;
  }
}

extern "C" void kernel_launch(void* const* d_in, const int* in_sizes, int n_in,
                              void* d_out, int out_size, void* d_ws, size_t ws_size,
                              hipStream_t stream) {
  const float* x  = (const float*)d_in[0];
  const int*   eg = (const int*)d_in[1];
  const float* W0 = (const float*)d_in[2];
  const float* W1 = (const float*)d_in[3];
  const float* W2 = (const float*)d_in[4];
  float* out = (float*)d_out;

  const int N = in_sizes[0] / N_FEAT0;  // 100000
  const int E = in_sizes[1] / 2;        // 1600000
  const int* esrc = eg;
  const int* edst = eg + E;
  const int nbuck = (N + BSZ - 1) >> BSH;  // 196

  // workspace layout (256B aligned)
  char* p = (char*)d_ws;
  auto alloc = [&](size_t bytes) {
    char* r = p;
    p += (bytes + 255) & ~(size_t)255;
    return r;
  };
  int*    bfill   = (int*)alloc(256 * 4);
  int*    bbase   = (int*)alloc(260 * 4);
  int*    row_ptr = (int*)alloc((size_t)(N + 1) * 4);
  float*  dinv    = (float*)alloc((size_t)N * 4);
  int*    ew      = (int*)alloc((size_t)E * 4);
  __half* bufG1   = (__half*)alloc((size_t)N * HID * 2);   // 12.8 MB
  __half* bufG2   = (__half*)alloc((size_t)N * HID * 2);   // 12.8 MB
  __half* bufG3   = (__half*)alloc((size_t)N * NCLS * 2);  // 8 MB
  // slab aliases bufG1 (9.63 MB <= 12.8 MB); build reads it before gemm0
  // writes bufG1 (stream-ordered).
  int* slab = (int*)bufG1;

  hipMemsetAsync(bfill, 0, 256 * 4, stream);

  const int sblocks = (E + STILE - 1) / STILE;  // 98
  scatter_kernel<<<sblocks, 256, 0, stream>>>(esrc, edst, bfill, slab, E);
  bscan_kernel<<<1, 256, 0, stream>>>(bfill, bbase, row_ptr, nbuck, N);
  build_kernel<<<nbuck, 256, 0, stream>>>(slab, bfill, bbase, row_ptr, dinv, ew, N);

  const int gblocks = (N + 127) / 128;
  const int ablocks = (N + 3) / 4;
  const int fblocks = 2048;
  // layer 0: 128 -> 64 (dense)
  gemm_kernel<128, 64><<<gblocks, 256, 0, stream>>>(x, W0, bufG1, dinv, N);
  // layer 1: agg + (64 -> 64) fused
  fused_kernel<64><<<fblocks, 256, 0, stream>>>(bufG1, row_ptr, ew, dinv, W1, bufG2, N);
  // layer 2: agg + (64 -> 40) fused
  fused_kernel<40><<<fblocks, 256, 0, stream>>>(bufG2, row_ptr, ew, dinv, W2, bufG3, N);
  // final aggregation -> output
  agg_kernel<40><<<ablocks, 256, 0, stream>>>(bufG3, row_ptr, ew, dinv, out, N);
}